// Round 6
// baseline (222.246 us; speedup 1.0000x reference)
//
#include <hip/hip_runtime.h>
#include <hip/hip_bf16.h>

// SimpleGNN on MI355X — fp32 in/out, edge_index int32/int64 auto-detect.
// out[d] = di[d]*(S[d] @ M) + di[d]*cnt_col[d]*c + b2
//   M = W1^T W2^T [128x64], c = b1 @ W2^T [64]
//   S[d] = sum_{e: col_e=d} x[row_e],  di[d] = 1/deg_row[d] (0 if deg 0)
// R18: ATOMIC CSR build — the zero-global-atomic slab machinery (per-chunk
// histograms, 12.8MB slabs, 64-iter choff loops, 12 edge passes) is deleted.
// Measured basis: R13/R17 showed random L2 access ≈ streaming pass in cost;
// atomics are the same currency, and they remove ~38MB slab traffic + 10
// edge passes. 5 dispatches:
//   K0 zero[deg,cnt,counter]   K1 [M,c ∥ deg-count (1 edge pass, no-return
//   atomics)]   K2 scan (tiny)   K3 [place (1 edge pass, atomic cursors) ∥ y]
//   K4 agg (start = cursor-cnt+bscan)
// R11/R14/R16 lessons: phases latency-bound; only less machinery + more
// concurrency moves the total.

#define IN_CH   128
#define OUT_CH  64
#define MC_UNITS 33
#define YROWS   32
#define EPB     2048                     // edges per deg/place block
#define SMEM_FLOATS (IN_CH * OUT_CH + YROWS * (IN_CH + 4))   // 49664 B

typedef unsigned short u16;
typedef unsigned int u32;

static __device__ inline float bfu32_lo(u32 u) { return __uint_as_float(u << 16); }
static __device__ inline float bfu32_hi(u32 u) { return __uint_as_float(u & 0xffff0000u); }
static __device__ inline u16 f2bf(float f) {
    __hip_bfloat16 h = __float2bfloat16(f);
    return *reinterpret_cast<u16*>(&h);
}

// wave-parallel stride detect: int64 edge_index => odd int32 words all 0
static __device__ inline int detect_stride_wave(const int* __restrict__ ei) {
    int lane = threadIdx.x & 63;
    int idx = (lane < 32) ? (2 * lane + 1) : 1;
    int v = ei[idx];
    unsigned long long m = __ballot((v != 0) && (lane < 32));
    return (m == 0ull) ? 2 : 1;
}

// ---- y tile unit (32 rows) ----
static __device__ inline void y_unit(int t, const float* __restrict__ x,
                                     const float* __restrict__ M,
                                     u16* __restrict__ y, float* smem,
                                     int n_nodes) {
    int tid = threadIdx.x;
    float* Ms = smem;
    float (*xs)[IN_CH + 4] = (float(*)[IN_CH + 4])(smem + IN_CH * OUT_CH);
    int tx = tid & 15;
    int ty = tid >> 4;
    int row0 = t * YROWS;
    if (row0 >= n_nodes) return;   // block-uniform

    const float4* Mv = (const float4*)M;
    float4* Msv = (float4*)Ms;
#pragma unroll
    for (int k = 0; k < 8; ++k) Msv[tid + 256 * k] = Mv[tid + 256 * k];

    for (int f = tid; f < YROWS * 32; f += 256) {
        int r = f >> 5, kq = f & 31;
        float4 v = make_float4(0.f, 0.f, 0.f, 0.f);
        if (row0 + r < n_nodes)
            v = *(const float4*)&x[(size_t)(row0 + r) * IN_CH + 4 * kq];
        *(float4*)&xs[r][4 * kq] = v;
    }
    __syncthreads();

    float4 acc0 = make_float4(0.f, 0.f, 0.f, 0.f);
    float4 acc1 = make_float4(0.f, 0.f, 0.f, 0.f);

    for (int k = 0; k < IN_CH; k += 4) {
        float4 xr0 = *(const float4*)&xs[ty][k];
        float4 xr1 = *(const float4*)&xs[ty + 16][k];
        float4 m0 = *(const float4*)&Ms[(k + 0) * OUT_CH + 4 * tx];
        float4 m1 = *(const float4*)&Ms[(k + 1) * OUT_CH + 4 * tx];
        float4 m2 = *(const float4*)&Ms[(k + 2) * OUT_CH + 4 * tx];
        float4 m3 = *(const float4*)&Ms[(k + 3) * OUT_CH + 4 * tx];
        acc0.x = fmaf(xr0.x, m0.x, acc0.x); acc0.y = fmaf(xr0.x, m0.y, acc0.y);
        acc0.z = fmaf(xr0.x, m0.z, acc0.z); acc0.w = fmaf(xr0.x, m0.w, acc0.w);
        acc0.x = fmaf(xr0.y, m1.x, acc0.x); acc0.y = fmaf(xr0.y, m1.y, acc0.y);
        acc0.z = fmaf(xr0.y, m1.z, acc0.z); acc0.w = fmaf(xr0.y, m1.w, acc0.w);
        acc0.x = fmaf(xr0.z, m2.x, acc0.x); acc0.y = fmaf(xr0.z, m2.y, acc0.y);
        acc0.z = fmaf(xr0.z, m2.z, acc0.z); acc0.w = fmaf(xr0.z, m2.w, acc0.w);
        acc0.x = fmaf(xr0.w, m3.x, acc0.x); acc0.y = fmaf(xr0.w, m3.y, acc0.y);
        acc0.z = fmaf(xr0.w, m3.z, acc0.z); acc0.w = fmaf(xr0.w, m3.w, acc0.w);
        acc1.x = fmaf(xr1.x, m0.x, acc1.x); acc1.y = fmaf(xr1.x, m0.y, acc1.y);
        acc1.z = fmaf(xr1.x, m0.z, acc1.z); acc1.w = fmaf(xr1.x, m0.w, acc1.w);
        acc1.x = fmaf(xr1.y, m1.x, acc1.x); acc1.y = fmaf(xr1.y, m1.y, acc1.y);
        acc1.z = fmaf(xr1.y, m1.z, acc1.z); acc1.w = fmaf(xr1.y, m1.w, acc1.w);
        acc1.x = fmaf(xr1.z, m2.x, acc1.x); acc1.y = fmaf(xr1.z, m2.y, acc1.y);
        acc1.z = fmaf(xr1.z, m2.z, acc1.z); acc1.w = fmaf(xr1.z, m2.w, acc1.w);
        acc1.x = fmaf(xr1.w, m3.x, acc1.x); acc1.y = fmaf(xr1.w, m3.y, acc1.y);
        acc1.z = fmaf(xr1.w, m3.z, acc1.z); acc1.w = fmaf(xr1.w, m3.w, acc1.w);
    }

    int r0 = row0 + ty;
    int r1 = row0 + ty + 16;
    if (r0 < n_nodes) {
        ushort4 s4;
        s4.x = f2bf(acc0.x); s4.y = f2bf(acc0.y);
        s4.z = f2bf(acc0.z); s4.w = f2bf(acc0.w);
        *(ushort4*)&y[(size_t)r0 * OUT_CH + 4 * tx] = s4;
    }
    if (r1 < n_nodes) {
        ushort4 s4;
        s4.x = f2bf(acc1.x); s4.y = f2bf(acc1.y);
        s4.z = f2bf(acc1.z); s4.w = f2bf(acc1.w);
        *(ushort4*)&y[(size_t)r1 * OUT_CH + 4 * tx] = s4;
    }
}

// ================= K0: zero deg/cnt/counter =================
__global__ __launch_bounds__(256) void mk_zero(float4* __restrict__ p, int n4,
                                               int* __restrict__ counter) {
    int i = blockIdx.x * 256 + threadIdx.x;
    if (i < n4) p[i] = make_float4(0.f, 0.f, 0.f, 0.f);
    if (i == 0) *counter = 0;
}

// ================= K1: [M,c | deg-count] =================
// deg blocks: 8 consecutive edges per thread — each lane's row-loads sit in
// ONE 64B line (int64 stride), col likewise; 16 no-return atomics/thread.
__global__ __launch_bounds__(256) void mk_prep(const float* __restrict__ W1,
                                               const float* __restrict__ b1,
                                               const float* __restrict__ W2,
                                               const int* __restrict__ ei,
                                               float* __restrict__ M,
                                               float* __restrict__ c,
                                               int* __restrict__ deg_row,
                                               int* __restrict__ cnt_col,
                                               int n_edges, int n_nodes) {
    int b = blockIdx.x;
    int tid = threadIdx.x;
    if (b < MC_UNITS) {
        int t = b * 256 + tid;
        if (t < IN_CH * OUT_CH) {
            int o = t & (OUT_CH - 1);
            int i = t >> 6;
            float acc = 0.f;
            for (int h = 0; h < 128; ++h)
                acc += W1[h * 128 + i] * W2[o * 128 + h];
            M[i * OUT_CH + o] = acc;
        } else if (t < IN_CH * OUT_CH + OUT_CH) {
            int o = t - IN_CH * OUT_CH;
            float acc = 0.f;
            for (int h = 0; h < 128; ++h)
                acc += b1[h] * W2[o * 128 + h];
            c[o] = acc;
        }
        return;
    }
    // ---- deg: one streaming pass ----
    int db = b - MC_UNITS;
    size_t e0 = (size_t)db * EPB;
    if (e0 >= (size_t)n_edges) return;
    int stride = detect_stride_wave(ei);
    const int* rp = ei;
    const int* cp = ei + (size_t)n_edges * stride;

    size_t i0 = e0 + (size_t)tid * 8;
    if (i0 + 8 <= (size_t)n_edges) {
        int s8[8], d8[8];
#pragma unroll
        for (int k = 0; k < 8; ++k) s8[k] = rp[(i0 + k) * stride];
#pragma unroll
        for (int k = 0; k < 8; ++k) d8[k] = cp[(i0 + k) * stride];
#pragma unroll
        for (int k = 0; k < 8; ++k) {
            if ((unsigned)s8[k] < (unsigned)n_nodes) {
                atomicAdd(&deg_row[s8[k]], 1);
                if ((unsigned)d8[k] < (unsigned)n_nodes)
                    atomicAdd(&cnt_col[d8[k]], 1);
            }
        }
    } else {
        for (size_t i = i0; i < (size_t)n_edges && i < i0 + 8; ++i) {
            int ss = rp[i * stride];
            int dd = cp[i * stride];
            if ((unsigned)ss < (unsigned)n_nodes) {
                atomicAdd(&deg_row[ss], 1);
                if ((unsigned)dd < (unsigned)n_nodes)
                    atomicAdd(&cnt_col[dd], 1);
            }
        }
    }
}

// ================= K2: scan cnt_col; last block exports bscan_g =================
__global__ __launch_bounds__(256) void mk_scan(const int* __restrict__ cnt_col,
                                               int* __restrict__ cursor_part,
                                               int* __restrict__ bsums,
                                               int* __restrict__ counter,
                                               int* __restrict__ bscan_g,
                                               int n_nodes, int nb) {
    __shared__ int sm[256];
    __shared__ int islast;
    int b = blockIdx.x;
    int t = threadIdx.x;
    int n = b * 256 + t;
    int run = (n < n_nodes) ? cnt_col[n] : 0;
    sm[t] = run;
    __syncthreads();
    for (int d = 1; d < 256; d <<= 1) {
        int add = (t >= d) ? sm[t - d] : 0;
        __syncthreads();
        sm[t] += add;
        __syncthreads();
    }
    if (n < n_nodes) cursor_part[n] = sm[t] - run;   // block-relative start
    if (t == 255) bsums[b] = sm[t];

    __syncthreads();
    if (t == 0) {
        __threadfence();
        int old = atomicAdd(counter, 1);
        islast = (old == nb - 1);
    }
    __syncthreads();
    if (islast) {
        int v = (t < nb) ? atomicAdd(&bsums[t], 0) : 0;   // coherent read
        sm[t] = v;
        __syncthreads();
        for (int d = 1; d < 256; d <<= 1) {
            int add = (t >= d) ? sm[t - d] : 0;
            __syncthreads();
            sm[t] += add;
            __syncthreads();
        }
        bscan_g[t] = sm[t] - v;           // exclusive prefix across blocks
    }
}

// ================= K3: [place (atomic cursors) ∥ y] =================
// place: ONE pass; pos = atomicAdd(&cursor_part[d],1) (relative) + bscanL.
// After place, cursor_part[d] = rel_start + cnt_col[d] (K4 subtracts back).
__global__ __launch_bounds__(256) void mk_place_y(const int* __restrict__ ei,
                                                  int* __restrict__ cursor_part,
                                                  const int* __restrict__ bscan_g,
                                                  int* __restrict__ csr_src,
                                                  const float* __restrict__ x,
                                                  const float* __restrict__ M,
                                                  u16* __restrict__ y,
                                                  int n_edges, int n_nodes,
                                                  int place_blocks) {
    __shared__ float smem[SMEM_FLOATS];
    int b = blockIdx.x;
    int tid = threadIdx.x;

    if (b < place_blocks) {
        int* bscanL = (int*)smem;
        bscanL[tid] = bscan_g[tid];
        __syncthreads();

        size_t e0 = (size_t)b * EPB;
        if (e0 >= (size_t)n_edges) return;
        int stride = detect_stride_wave(ei);
        const int* rp = ei;
        const int* cp = ei + (size_t)n_edges * stride;

        size_t i0 = e0 + (size_t)tid * 8;
        if (i0 + 8 <= (size_t)n_edges) {
            int s8[8], d8[8], pos[8];
#pragma unroll
            for (int k = 0; k < 8; ++k) s8[k] = rp[(i0 + k) * stride];
#pragma unroll
            for (int k = 0; k < 8; ++k) d8[k] = cp[(i0 + k) * stride];
#pragma unroll
            for (int k = 0; k < 8; ++k) {
                bool v = (unsigned)d8[k] < (unsigned)n_nodes &&
                         (unsigned)s8[k] < (unsigned)n_nodes;
                pos[k] = v ? atomicAdd(&cursor_part[d8[k]], 1) : -1;
            }
#pragma unroll
            for (int k = 0; k < 8; ++k) {
                if (pos[k] >= 0)
                    csr_src[pos[k] + bscanL[d8[k] >> 8]] = s8[k];
            }
        } else {
            for (size_t i = i0; i < (size_t)n_edges && i < i0 + 8; ++i) {
                int ss = rp[i * stride];
                int dd = cp[i * stride];
                if ((unsigned)dd < (unsigned)n_nodes &&
                    (unsigned)ss < (unsigned)n_nodes) {
                    int p = atomicAdd(&cursor_part[dd], 1);
                    csr_src[p + bscanL[dd >> 8]] = ss;
                }
            }
        }
        return;
    }

    // ---- y tile ----
    y_unit(b - place_blocks, x, M, y, smem, n_nodes);
}

// ================= K4: agg_final (no LDS) =================
__global__ __launch_bounds__(256) void mk_agg_final(const int* __restrict__ cursor_part,
                                                    const int* __restrict__ bscan_g,
                                                    const int* __restrict__ cnt_col,
                                                    const int* __restrict__ csr_src,
                                                    const int* __restrict__ deg_row,
                                                    const uint2* __restrict__ yv,
                                                    const float* __restrict__ c,
                                                    const float* __restrict__ b2,
                                                    float* __restrict__ out,
                                                    int n_nodes) {
    int wave = threadIdx.x >> 6;
    int lane = threadIdx.x & 63;
    int dsub = lane >> 4;
    int ch   = lane & 15;
    int d = blockIdx.x * 16 + wave * 4 + dsub;
    if (d >= n_nodes) return;

    int cnt = cnt_col[d];
    int start = cursor_part[d] - cnt + bscan_g[d >> 8];   // place advanced it by cnt
    int end = start + cnt;
    int e1m = end - 1;
    float a0 = 0.f, a1 = 0.f, a2 = 0.f, a3 = 0.f;
    for (int j = start; j < end; j += 8) {
        int idx[8], srcs[8];
#pragma unroll
        for (int k = 0; k < 8; ++k) {
            int t = j + k;
            idx[k] = t > e1m ? e1m : t;
        }
#pragma unroll
        for (int k = 0; k < 8; ++k) srcs[k] = csr_src[idx[k]];
        uint2 u[8];
#pragma unroll
        for (int k = 0; k < 8; ++k) u[k] = yv[(size_t)srcs[k] * 16 + ch];
#pragma unroll
        for (int k = 1; k < 8; ++k)
            if (j + k >= end) { u[k].x = 0u; u[k].y = 0u; }
#pragma unroll
        for (int k = 0; k < 8; ++k) {
            a0 += bfu32_lo(u[k].x);
            a1 += bfu32_hi(u[k].x);
            a2 += bfu32_lo(u[k].y);
            a3 += bfu32_hi(u[k].y);
        }
    }
    int dr = deg_row[d];
    float di = (dr > 0) ? (1.0f / (float)dr) : 0.f;
    float fc = di * (float)cnt;
    float4 cv = ((const float4*)c)[ch];
    float4 bv = ((const float4*)b2)[ch];
    float4 o;
    o.x = di * a0 + fc * cv.x + bv.x;
    o.y = di * a1 + fc * cv.y + bv.y;
    o.z = di * a2 + fc * cv.z + bv.z;
    o.w = di * a3 + fc * cv.w + bv.w;
    ((float4*)(out + (size_t)d * OUT_CH))[ch] = o;
}

extern "C" void kernel_launch(void* const* d_in, const int* in_sizes, int n_in,
                              void* d_out, int out_size, void* d_ws, size_t ws_size,
                              hipStream_t stream) {
    const float* x  = (const float*)d_in[0];
    const int*   ei = (const int*)d_in[1];
    const float* W1 = (const float*)d_in[2];
    const float* b1 = (const float*)d_in[3];
    const float* W2 = (const float*)d_in[4];
    const float* b2 = (const float*)d_in[5];
    float* out = (float*)d_out;

    const int n_nodes = in_sizes[0] / IN_CH;     // 50000
    const int n_edges = in_sizes[1] / 2;         // 800000

    const size_t csr_bytes = ((size_t)n_edges * 4 + 127) & ~(size_t)127;

    char* ws = (char*)d_ws;
    float* M        = (float*)(ws);                    // 32768
    float* c        = (float*)(ws + 32768);            // 384
    int*   deg_row  = (int*)  (ws + 33152);            // 200064
    int*   cnt_col  = (int*)  (ws + 233216);           // 200064 (contiguous w/ deg)
    int*   cursor   = (int*)  (ws + 433280);           // 200064
    int*   bsums    = (int*)  (ws + 633344);           // 1024
    int*   bscan_g  = (int*)  (ws + 634368);           // 1024
    int*   counter  = (int*)  (ws + 635392);           // 128
    int*   csr_src  = (int*)  (ws + 635520);           // 3.2 MB
    u16*   y        = (u16*)  (ws + 635520 + csr_bytes);

    const int y_total = (n_nodes + YROWS - 1) / YROWS;     // 1563
    const int nb = (n_nodes + 255) / 256;                  // 196 (<=256 required)
    const int deg_blocks = (n_edges + EPB - 1) / EPB;      // 391
    const int zero_n4 = (2 * 200064) / 16;                 // deg_row+cnt_col

    mk_zero<<<(zero_n4 + 255) / 256, 256, 0, stream>>>(
        (float4*)deg_row, zero_n4, counter);

    mk_prep<<<MC_UNITS + deg_blocks, 256, 0, stream>>>(
        W1, b1, W2, ei, M, c, deg_row, cnt_col, n_edges, n_nodes);

    mk_scan<<<nb, 256, 0, stream>>>(cnt_col, cursor, bsums, counter, bscan_g,
                                    n_nodes, nb);

    mk_place_y<<<deg_blocks + y_total, 256, 0, stream>>>(
        ei, cursor, bscan_g, csr_src, x, M, y, n_edges, n_nodes, deg_blocks);

    mk_agg_final<<<(n_nodes + 15) / 16, 256, 0, stream>>>(
        cursor, bscan_g, cnt_col, csr_src, deg_row, (const uint2*)y, c, b2, out,
        n_nodes);
}